// Round 12
// baseline (355.866 us; speedup 1.0000x reference)
//
#include <hip/hip_runtime.h>
#include <cstdint>
#include <cstddef>

#define T_TOK 64
#define K_IN 4096
#define N_OUT 14336
#define SPLITK 16
#define KCHUNK 256                   // K per block (4096/16)
#define NSTAGES 8                    // 8 stages x 32 k
#define NCOLS 64                     // cols per block (16 per wave)

typedef __attribute__((ext_vector_type(8))) short bf16x8;
typedef __attribute__((ext_vector_type(4))) float f32x4;

static __device__ __forceinline__ unsigned short bf16_rne(float f) {
    unsigned u = __builtin_bit_cast(unsigned, f);
    unsigned r = (u + 0x7fffu + ((u >> 16) & 1u)) >> 16;
    return (unsigned short)r;
}

// Kernel 1: x (fp32) -> bf16 copy in ws + per-token row sums.
__global__ __launch_bounds__(256) void prep_kernel(const float* __restrict__ x,
                                                   unsigned short* __restrict__ xbf,
                                                   float* __restrict__ rowsum) {
    const int row = blockIdx.x;
    const int t = threadIdx.x;
    const float4* x4 = (const float4*)(x + (size_t)row * K_IN);
    float s = 0.f;
#pragma unroll
    for (int i = 0; i < 4; i++) {
        float4 v = x4[i * 256 + t];
        s += v.x + v.y + v.z + v.w;
        ushort4 h;
        h.x = bf16_rne(v.x); h.y = bf16_rne(v.y);
        h.z = bf16_rne(v.z); h.w = bf16_rne(v.w);
        *(ushort4*)(xbf + (size_t)row * K_IN + (size_t)(i * 256 + t) * 4) = h;
    }
#pragma unroll
    for (int off = 32; off > 0; off >>= 1) s += __shfl_down(s, off, 64);
    __shared__ float part[4];
    const int wave = t >> 6, lane = t & 63;
    if (lane == 0) part[wave] = s;
    __syncthreads();
    if (t == 0) rowsum[row] = part[0] + part[1] + part[2] + part[3];
}

// ---- manual-pipeline primitives: inline-asm loads + inline-asm vmcnt waits.
#define LOAD_B(dst, p) \
    asm volatile("global_load_dword %0, %1, off" : "=v"(dst) : "v"(p))

#define WAIT_B(cnt, B) \
    asm volatile("s_waitcnt vmcnt(" #cnt ")" \
        : "+v"((B)[0]), "+v"((B)[1]), "+v"((B)[2]), "+v"((B)[3]), \
          "+v"((B)[4]), "+v"((B)[5]), "+v"((B)[6]), "+v"((B)[7]))

#define ISSUE_B(S, B) \
    { \
        LOAD_B((B)[0], wlane + (size_t)((S) * 32 + 0) * N_OUT); \
        LOAD_B((B)[1], wlane + (size_t)((S) * 32 + 1) * N_OUT); \
        LOAD_B((B)[2], wlane + (size_t)((S) * 32 + 2) * N_OUT); \
        LOAD_B((B)[3], wlane + (size_t)((S) * 32 + 3) * N_OUT); \
        LOAD_B((B)[4], wlane + (size_t)((S) * 32 + 4) * N_OUT); \
        LOAD_B((B)[5], wlane + (size_t)((S) * 32 + 5) * N_OUT); \
        LOAD_B((B)[6], wlane + (size_t)((S) * 32 + 6) * N_OUT); \
        LOAD_B((B)[7], wlane + (size_t)((S) * 32 + 7) * N_OUT); \
    }

// Kernel 2: split-K int4-dequant GEMM (round-10 body). Epilogue stores
// NON-OVERLAPPING partials[sk][t][col] -- no atomics (rounds 8-10 were bound
// by 14.7M global atomic RMWs ~= 100 us, invariant across load pipelines).
__global__ __launch_bounds__(256, 3) void gemm_kernel(const unsigned short* __restrict__ xbf,
                                                      const int* __restrict__ W,
                                                      const float* __restrict__ scales,
                                                      float* __restrict__ partials) {
    __shared__ char Alds[32768];

    const int tid = threadIdx.x;
    const int wave = tid >> 6;
    const int lane = tid & 63;
    const int q = lane >> 4;            // quad: k-offset q*8 in frags
    const int r = lane & 15;            // col within wave strip / token row
    const int cb = blockIdx.x;
    const int kbase = blockIdx.y * KCHUNK;
    const int col = cb * NCOLS + wave * 16 + r;

    const int g0 = kbase >> 7;
    float sc0 = scales[(size_t)g0 * N_OUT + col];
    float sc1 = scales[(size_t)(g0 + 1) * N_OUT + col];
    asm volatile("" : "+v"(sc0), "+v"(sc1));   // pin: materialized pre-barrier

    // ---- stage A once: 64 rows x 512 B, 16-B chunk cc stored at cc^(row&7)
    {
        int4 av[8];
#pragma unroll
        for (int i = 0; i < 8; i++) {
            const int chunk = i * 256 + tid;           // 2048 chunks of 16 B
            const int row = chunk >> 5;
            const int cc = chunk & 31;
            av[i] = *(const int4*)(xbf + (size_t)row * K_IN + kbase + cc * 8);
        }
#pragma unroll
        for (int i = 0; i < 8; i++) {
            const int chunk = i * 256 + tid;
            const int row = chunk >> 5;
            const int cc = chunk & 31;
            *(int4*)(Alds + row * 512 + (cc ^ (row & 7)) * 16) = av[i];
        }
    }
    __syncthreads();   // ONLY barrier: A visible; all compiler vmem drained

    const int* wlane = W + (size_t)(kbase + q * 8) * N_OUT + col;

    f32x4 acc[4];
#pragma unroll
    for (int mt = 0; mt < 4; mt++) acc[mt] = f32x4{0.f, 0.f, 0.f, 0.f};

    auto consume = [&](int s, int (&B)[8]) {
        const float scs = (s < 4) ? sc0 : sc1;        // group = (kbase+s*32)/128
        bf16x8 bf;
#pragma unroll
        for (int j = 0; j < 8; j++) bf[j] = (short)bf16_rne((float)B[j] * scs);
#pragma unroll
        for (int mt = 0; mt < 4; mt++) {
            const int row = r + mt * 16;
            bf16x8 af = *(const bf16x8*)(Alds + row * 512 + (((s * 4 + q) ^ (r & 7)) << 4));
            acc[mt] = __builtin_amdgcn_mfma_f32_16x16x32_bf16(af, bf, acc[mt], 0, 0, 0);
        }
    };

    int b0[8], b1[8];
    ISSUE_B(0, b0); ISSUE_B(1, b1);
    WAIT_B(8, b0); consume(0, b0); ISSUE_B(2, b0);
    WAIT_B(8, b1); consume(1, b1); ISSUE_B(3, b1);
    WAIT_B(8, b0); consume(2, b0); ISSUE_B(4, b0);
    WAIT_B(8, b1); consume(3, b1); ISSUE_B(5, b1);
    WAIT_B(8, b0); consume(4, b0); ISSUE_B(6, b0);
    WAIT_B(8, b1); consume(5, b1); ISSUE_B(7, b1);
    WAIT_B(8, b0); consume(6, b0);
    WAIT_B(0, b1); consume(7, b1);

    // epilogue: plain stores to this split's private partial slab.
    // C/D layout: row t = mt*16 + q*4 + i, col = col.
    float* pb = partials + ((size_t)blockIdx.y * T_TOK) * N_OUT + col;
#pragma unroll
    for (int mt = 0; mt < 4; mt++) {
#pragma unroll
        for (int i = 0; i < 4; i++) {
            const int t = mt * 16 + q * 4 + i;
            pb[(size_t)t * N_OUT] = acc[mt][i];
        }
    }
}

// Kernel 3: out[t][col] = bias + rowsum[t]*u + sum_sk partials[sk][t][col].
// Grid (N_OUT/4/256, T_TOK) x 256 thr, float4 per thread.
__global__ __launch_bounds__(256) void reduce_kernel(const float* __restrict__ partials,
                                                     const float* __restrict__ rowsum,
                                                     const float* __restrict__ u,
                                                     const float* __restrict__ bias,
                                                     float* __restrict__ out) {
    const int t = blockIdx.y;
    const int n4 = blockIdx.x * 256 + threadIdx.x;      // float4 index within row
    const float rs = rowsum[t];
    float4 b = ((const float4*)bias)[n4];
    float4 uu = ((const float4*)u)[n4];
    float4 s;
    s.x = b.x + rs * uu.x; s.y = b.y + rs * uu.y;
    s.z = b.z + rs * uu.z; s.w = b.w + rs * uu.w;
    const float4* p = (const float4*)(partials + (size_t)t * N_OUT) + n4;
#pragma unroll
    for (int sk = 0; sk < SPLITK; sk++) {
        float4 v = p[(size_t)sk * (T_TOK * N_OUT / 4)];
        s.x += v.x; s.y += v.y; s.z += v.z; s.w += v.w;
    }
    ((float4*)(out + (size_t)t * N_OUT))[n4] = s;
}

extern "C" void kernel_launch(void* const* d_in, const int* in_sizes, int n_in,
                              void* d_out, int out_size, void* d_ws, size_t ws_size,
                              hipStream_t stream) {
    const float* x      = (const float*)d_in[0];
    const int*   W      = (const int*)d_in[1];
    const float* scales = (const float*)d_in[2];
    const float* u      = (const float*)d_in[3];
    const float* bias   = (const float*)d_in[4];
    float* out = (float*)d_out;

    unsigned short* xbf = (unsigned short*)d_ws;                 // 512 KB
    float* rowsum   = (float*)((char*)d_ws + (512 << 10));       // 256 B
    float* partials = (float*)((char*)d_ws + (1 << 20));         // 16*64*14336*4 = 58.7 MB

    prep_kernel<<<T_TOK, 256, 0, stream>>>(x, xbf, rowsum);
    gemm_kernel<<<dim3(N_OUT / NCOLS, SPLITK), 256, 0, stream>>>(xbf, W, scales, partials);
    reduce_kernel<<<dim3(N_OUT / 4 / 256, T_TOK), 256, 0, stream>>>(partials, rowsum, u, bias, out);
}

// Round 13
// 349.016 us; speedup vs baseline: 1.0196x; 1.0196x over previous
//
#include <hip/hip_runtime.h>
#include <cstdint>
#include <cstddef>

#define T_TOK 64
#define K_IN 4096
#define N_OUT 14336
#define SPLITK 16
#define KCHUNK 256                   // K per block (4096/16)
#define NSTAGES 8                    // 8 stages x 32 k
#define WCOLS 64                     // cols per wave (4 interleaved 16-col tiles)
#define BCOLS 128                    // cols per block (2 waves)

typedef __attribute__((ext_vector_type(8))) short bf16x8;
typedef __attribute__((ext_vector_type(4))) float f32x4;
typedef __attribute__((ext_vector_type(4))) int i32x4;

static __device__ __forceinline__ unsigned short bf16_rne(float f) {
    unsigned u = __builtin_bit_cast(unsigned, f);
    unsigned r = (u + 0x7fffu + ((u >> 16) & 1u)) >> 16;
    return (unsigned short)r;
}

// Kernel 1: x (fp32) -> bf16 copy in ws + per-token row sums.
__global__ __launch_bounds__(256) void prep_kernel(const float* __restrict__ x,
                                                   unsigned short* __restrict__ xbf,
                                                   float* __restrict__ rowsum) {
    const int row = blockIdx.x;
    const int t = threadIdx.x;
    const float4* x4 = (const float4*)(x + (size_t)row * K_IN);
    float s = 0.f;
#pragma unroll
    for (int i = 0; i < 4; i++) {
        float4 v = x4[i * 256 + t];
        s += v.x + v.y + v.z + v.w;
        ushort4 h;
        h.x = bf16_rne(v.x); h.y = bf16_rne(v.y);
        h.z = bf16_rne(v.z); h.w = bf16_rne(v.w);
        *(ushort4*)(xbf + (size_t)row * K_IN + (size_t)(i * 256 + t) * 4) = h;
    }
#pragma unroll
    for (int off = 32; off > 0; off >>= 1) s += __shfl_down(s, off, 64);
    __shared__ float part[4];
    const int wave = t >> 6, lane = t & 63;
    if (lane == 0) part[wave] = s;
    __syncthreads();
    if (t == 0) rowsum[row] = part[0] + part[1] + part[2] + part[3];
}

// ---- manual-pipeline primitives: inline-asm dwordx4 loads + vmcnt waits.
// 16 B/lane = 1 KB per wave-instr (the measured-optimal width; rounds 4-12
// plateaued at ~2.3 TB/s with 4-8 B/lane gathers regardless of pipelining).
#define LOAD_B4(dst, p) \
    asm volatile("global_load_dwordx4 %0, %1, off" : "=v"(dst) : "v"(p))

#define WAIT_B4(cnt, B) \
    asm volatile("s_waitcnt vmcnt(" #cnt ")" \
        : "+v"((B)[0]), "+v"((B)[1]), "+v"((B)[2]), "+v"((B)[3]), \
          "+v"((B)[4]), "+v"((B)[5]), "+v"((B)[6]), "+v"((B)[7]))

#define ISSUE_B4(S, B) \
    { \
        LOAD_B4((B)[0], wlane + (size_t)((S) * 32 + 0) * N_OUT); \
        LOAD_B4((B)[1], wlane + (size_t)((S) * 32 + 1) * N_OUT); \
        LOAD_B4((B)[2], wlane + (size_t)((S) * 32 + 2) * N_OUT); \
        LOAD_B4((B)[3], wlane + (size_t)((S) * 32 + 3) * N_OUT); \
        LOAD_B4((B)[4], wlane + (size_t)((S) * 32 + 4) * N_OUT); \
        LOAD_B4((B)[5], wlane + (size_t)((S) * 32 + 5) * N_OUT); \
        LOAD_B4((B)[6], wlane + (size_t)((S) * 32 + 6) * N_OUT); \
        LOAD_B4((B)[7], wlane + (size_t)((S) * 32 + 7) * N_OUT); \
    }

// Kernel 2: split-K int4-dequant GEMM, dwordx4 W loads.
// Grid (112, 16) x 128 thr (2 waves). Wave owns 64 cols as 4 column-interleaved
// MFMA tiles: tile c covers actual cols colbase + 4*r + c (r = tile col index).
// Lane (q,r) loads W[k=kbase+s*32+q*8+j][colbase+4r .. +3] as one dwordx4.
// Depth-2 asm pipeline, waits vmcnt(8)/(0). A (64x256 bf16, 32 KB) staged to
// LDS once, XOR-swizzled. Epilogue: float4 partial stores (no atomics).
__global__ __launch_bounds__(128, 2) void gemm_kernel(const unsigned short* __restrict__ xbf,
                                                      const int* __restrict__ W,
                                                      const float* __restrict__ scales,
                                                      float* __restrict__ partials) {
    __shared__ char Alds[32768];

    const int tid = threadIdx.x;
    const int wave = tid >> 6;          // 0..1
    const int lane = tid & 63;
    const int q = lane >> 4;            // quad: k-offset q*8 in frags
    const int r = lane & 15;            // tile col index / token row
    const int cb = blockIdx.x;
    const int kbase = blockIdx.y * KCHUNK;
    const int colbase = cb * BCOLS + wave * WCOLS;
    const int mycol = colbase + 4 * r;  // lane's 4 consecutive cols

    // per-col scales for the two 128-groups of this k-chunk; pinned so the
    // loads retire before the barrier (no compiler vmcnt(0) in the K-loop)
    const int g0 = kbase >> 7;
    float4 sc0 = *(const float4*)(scales + (size_t)g0 * N_OUT + mycol);
    float4 sc1 = *(const float4*)(scales + (size_t)(g0 + 1) * N_OUT + mycol);
    asm volatile("" : "+v"(sc0.x), "+v"(sc0.y), "+v"(sc0.z), "+v"(sc0.w),
                      "+v"(sc1.x), "+v"(sc1.y), "+v"(sc1.z), "+v"(sc1.w));

    // ---- stage A once: 64 rows x 512 B, 16-B chunk cc stored at cc^(row&7)
#pragma unroll
    for (int half = 0; half < 2; half++) {
        i32x4 av[8];
#pragma unroll
        for (int i = 0; i < 8; i++) {
            const int chunk = (half * 8 + i) * 128 + tid;   // 2048 chunks of 16 B
            const int row = chunk >> 5;
            const int cc = chunk & 31;
            av[i] = *(const i32x4*)(xbf + (size_t)row * K_IN + kbase + cc * 8);
        }
#pragma unroll
        for (int i = 0; i < 8; i++) {
            const int chunk = (half * 8 + i) * 128 + tid;
            const int row = chunk >> 5;
            const int cc = chunk & 31;
            *(i32x4*)(Alds + row * 512 + (cc ^ (row & 7)) * 16) = av[i];
        }
    }
    __syncthreads();   // ONLY barrier: A visible; all compiler vmem drained

    const int* wlane = W + (size_t)(kbase + q * 8) * N_OUT + mycol;

    f32x4 acc[4][4];   // [col-tile c][M-tile mt]
#pragma unroll
    for (int c = 0; c < 4; c++)
#pragma unroll
        for (int mt = 0; mt < 4; mt++) acc[c][mt] = f32x4{0.f, 0.f, 0.f, 0.f};

    auto consume = [&](int s, i32x4 (&B)[8]) {
        const float4 scv = (s < 4) ? sc0 : sc1;       // group = (kbase+s*32)/128
        const float scs[4] = {scv.x, scv.y, scv.z, scv.w};
        bf16x8 bf[4];
#pragma unroll
        for (int c = 0; c < 4; c++)
#pragma unroll
            for (int j = 0; j < 8; j++)
                bf[c][j] = (short)bf16_rne((float)B[j][c] * scs[c]);
#pragma unroll
        for (int mt = 0; mt < 4; mt++) {
            bf16x8 af = *(const bf16x8*)(Alds + (r + mt * 16) * 512 + (((s * 4 + q) ^ (r & 7)) << 4));
#pragma unroll
            for (int c = 0; c < 4; c++)
                acc[c][mt] = __builtin_amdgcn_mfma_f32_16x16x32_bf16(af, bf[c], acc[c][mt], 0, 0, 0);
        }
    };

    i32x4 b0[8], b1[8];
    ISSUE_B4(0, b0); ISSUE_B4(1, b1);
    WAIT_B4(8, b0); consume(0, b0); ISSUE_B4(2, b0);
    WAIT_B4(8, b1); consume(1, b1); ISSUE_B4(3, b1);
    WAIT_B4(8, b0); consume(2, b0); ISSUE_B4(4, b0);
    WAIT_B4(8, b1); consume(3, b1); ISSUE_B4(5, b1);
    WAIT_B4(8, b0); consume(4, b0); ISSUE_B4(6, b0);
    WAIT_B4(8, b1); consume(5, b1); ISSUE_B4(7, b1);
    WAIT_B4(8, b0); consume(6, b0);
    WAIT_B4(0, b1); consume(7, b1);

    // epilogue: float4 partial stores. D tile c: row t = mt*16+q*4+i,
    // actual col = mycol + c -> the 4 tiles pack into one float4 per lane.
    float* pb = partials + (size_t)blockIdx.y * T_TOK * N_OUT + mycol;
#pragma unroll
    for (int mt = 0; mt < 4; mt++) {
#pragma unroll
        for (int i = 0; i < 4; i++) {
            const int t = mt * 16 + q * 4 + i;
            float4 v;
            v.x = acc[0][mt][i]; v.y = acc[1][mt][i];
            v.z = acc[2][mt][i]; v.w = acc[3][mt][i];
            *(float4*)(pb + (size_t)t * N_OUT) = v;
        }
    }
}

// Kernel 3: out[t][col] = bias + rowsum[t]*u + sum_sk partials[sk][t][col].
// Grid (N_OUT/4/256, T_TOK) x 256 thr, float4 per thread.
__global__ __launch_bounds__(256) void reduce_kernel(const float* __restrict__ partials,
                                                     const float* __restrict__ rowsum,
                                                     const float* __restrict__ u,
                                                     const float* __restrict__ bias,
                                                     float* __restrict__ out) {
    const int t = blockIdx.y;
    const int n4 = blockIdx.x * 256 + threadIdx.x;      // float4 index within row
    const float rs = rowsum[t];
    float4 b = ((const float4*)bias)[n4];
    float4 uu = ((const float4*)u)[n4];
    float4 s;
    s.x = b.x + rs * uu.x; s.y = b.y + rs * uu.y;
    s.z = b.z + rs * uu.z; s.w = b.w + rs * uu.w;
    const float4* p = (const float4*)(partials + (size_t)t * N_OUT) + n4;
#pragma unroll
    for (int sk = 0; sk < SPLITK; sk++) {
        float4 v = p[(size_t)sk * (T_TOK * N_OUT / 4)];
        s.x += v.x; s.y += v.y; s.z += v.z; s.w += v.w;
    }
    ((float4*)(out + (size_t)t * N_OUT))[n4] = s;
}

extern "C" void kernel_launch(void* const* d_in, const int* in_sizes, int n_in,
                              void* d_out, int out_size, void* d_ws, size_t ws_size,
                              hipStream_t stream) {
    const float* x      = (const float*)d_in[0];
    const int*   W      = (const int*)d_in[1];
    const float* scales = (const float*)d_in[2];
    const float* u      = (const float*)d_in[3];
    const float* bias   = (const float*)d_in[4];
    float* out = (float*)d_out;

    unsigned short* xbf = (unsigned short*)d_ws;                 // 512 KB
    float* rowsum   = (float*)((char*)d_ws + (512 << 10));       // 256 B
    float* partials = (float*)((char*)d_ws + (1 << 20));         // 16*64*14336*4 = 58.7 MB

    prep_kernel<<<T_TOK, 256, 0, stream>>>(x, xbf, rowsum);
    gemm_kernel<<<dim3(N_OUT / BCOLS, SPLITK), 128, 0, stream>>>(xbf, W, scales, partials);
    reduce_kernel<<<dim3(N_OUT / 4 / 256, T_TOK), 256, 0, stream>>>(partials, rowsum, u, bias, out);
}